// Round 8
// baseline (273.975 us; speedup 1.0000x reference)
//
#include <hip/hip_runtime.h>

#define N_NODES_C 1000
#define N_EDGES_C 8000
#define BATCH_C   64
#define IN_DIM_C  64
#define HID_C     128
#define NT (BATCH_C * N_NODES_C)   // 64000 total nodes
#define ET (BATCH_C * N_EDGES_C)   // 512000 total edges

// workspace layout (float offsets) -- byte-identical footprint to round 4
#define WS_DEG    0                 // 64000 f: deg -> dinv (in place)
#define WS_EWS    64000             // 8000 f: sparsified edge weights
#define WS_CNT    72000             // 64000 i: dst counts
#define WS_CUR    136000            // 64000 i: scatter cursors
#define WS_ROWP   200000            // 64*1024 i: per-graph CSR row starts
#define WS_PEDGE  265536            // 512000 int2: (src_global, norm) CSR order
// PART overlaps CNT..PEDGE (dead by the time reduce_g runs): 800*2048 floats
#define WS_PART2  72000             // 72000..1710400 < WS_H2 ✓
#define WS_H2     1813824           // 8192000 f: h2 (gemm output)
#define WS_RH     10005824          // 8192000 f: relu_h (if ws_size permits)
#define RG_BLOCKS 800               // k-chunks of 160

// ---------------------------------------------------------------- prep ----
__global__ __launch_bounds__(256) void prep(const float* __restrict__ ew_in,
                                            const float* __restrict__ ni,
                                            float* __restrict__ ws,
                                            float* __restrict__ out) {
    int i = blockIdx.x * 256 + threadIdx.x;       // grid covers 64000
    if (i < NT) {
        ws[WS_DEG + i] = 1.0f;
        ((int*)(ws + WS_CNT))[i] = 0;
    }
    if (i < N_EDGES_C) {
        float w = ew_in[i];
        float s = (w < 0.2f) ? 0.0f : fminf(w, 1.0f);
        ws[WS_EWS + i] = s;
        out[128 + i] = s;                         // output 1: ew
    }
    if (i < N_NODES_C) {
        float v = ni[i];
        out[128 + N_EDGES_C + i] = fminf(fmaxf(v, 0.0f), 1.0f);  // output 2
    }
}

// ----------------------------------------------- weighted degree + count --
__global__ __launch_bounds__(256) void deg_cnt(const int* __restrict__ ei,
                                               float* __restrict__ ws) {
    int e = blockIdx.x * 256 + threadIdx.x;       // < ET
    int d = ei[ET + e];
    int le = e % N_EDGES_C;
    atomicAdd(&ws[WS_DEG + d], ws[WS_EWS + le]);
    atomicAdd(&((int*)(ws + WS_CNT))[d], 1);
}

// --------------------------------- per-graph: dinv + scan(cnt) -> rowp ----
__global__ __launch_bounds__(256) void csr_scan(float* __restrict__ ws) {
    __shared__ int rs[N_NODES_C + 8];
    __shared__ int wtot[4];
    int g = blockIdx.x, tid = threadIdx.x;
    int lane = tid & 63, wid = tid >> 6;
    int gbase = g * N_NODES_C;
    const int* cnt = (const int*)(ws + WS_CNT) + gbase;

    // deg -> dinv (in place)
    for (int i = tid; i < N_NODES_C; i += 256)
        ws[WS_DEG + gbase + i] = rsqrtf(ws[WS_DEG + gbase + i]);

    // exclusive scan of cnt (4 per thread + shfl scan)
    int s0 = 0, s1 = 0, s2 = 0, s3 = 0, tsum = 0;
    if (tid < 250) {
        s0 = cnt[4 * tid]; s1 = cnt[4 * tid + 1];
        s2 = cnt[4 * tid + 2]; s3 = cnt[4 * tid + 3];
        tsum = s0 + s1 + s2 + s3;
    }
    int v = tsum;
    #pragma unroll
    for (int off = 1; off < 64; off <<= 1) {
        int n = __shfl_up(v, off, 64);
        if (lane >= off) v += n;
    }
    if (lane == 63) wtot[wid] = v;
    __syncthreads();
    int base = 0;
    for (int w = 0; w < wid; ++w) base += wtot[w];
    int excl = base + v - tsum;
    if (tid < 250) {
        rs[4 * tid]     = excl;
        rs[4 * tid + 1] = excl + s0;
        rs[4 * tid + 2] = excl + s0 + s1;
        rs[4 * tid + 3] = excl + s0 + s1 + s2;
    }
    if (tid == 255) rs[N_NODES_C] = N_EDGES_C;
    __syncthreads();

    int* rowp = (int*)(ws + WS_ROWP) + g * 1024;
    int* cur  = (int*)(ws + WS_CUR) + gbase;
    for (int i = tid; i <= N_NODES_C; i += 256) rowp[i] = rs[i];
    for (int i = tid; i < N_NODES_C; i += 256) cur[i] = rs[i];
}

// ------------------------------------- scatter (src, norm) into CSR order -
__global__ __launch_bounds__(256) void scatter(const int* __restrict__ ei,
                                               float* __restrict__ ws) {
    int e = blockIdx.x * 256 + threadIdx.x;       // < ET
    int g = e / N_EDGES_C;
    int le = e - g * N_EDGES_C;
    int s = ei[e];
    int d = ei[ET + e];
    const float* dinv = ws + WS_DEG;
    float nm = dinv[s] * ws[WS_EWS + le] * dinv[d];
    int pos = atomicAdd(&((int*)(ws + WS_CUR))[d], 1);
    ((int2*)(ws + WS_PEDGE))[g * N_EDGES_C + pos] =
        make_int2(s, __float_as_int(nm));
}

// ------------------------------------------------------- h2 = (x*ni) @ W1 -
__global__ __launch_bounds__(256) void gemm_h2(const float* __restrict__ x,
                                               const float* __restrict__ ni,
                                               const float* __restrict__ W1,
                                               float* __restrict__ h2) {
    __shared__ float xs[128][65];
    __shared__ float wsm[64 * 128];
    int tid = threadIdx.x;
    int base = blockIdx.x * 128;

    #pragma unroll
    for (int i = 0; i < 8; ++i) {
        int idx = i * 1024 + tid * 4;
        int r = idx >> 6, d = idx & 63;
        float4 v = *(const float4*)&x[(base + r) * 64 + d];
        float s = ni[(base + r) % N_NODES_C];
        xs[r][d + 0] = v.x * s;
        xs[r][d + 1] = v.y * s;
        xs[r][d + 2] = v.z * s;
        xs[r][d + 3] = v.w * s;
    }
    #pragma unroll
    for (int i = 0; i < 8; ++i) {
        int idx = i * 1024 + tid * 4;
        *(float4*)&wsm[idx] = *(const float4*)&W1[idx];
    }
    __syncthreads();

    int tx = tid & 15, ty = tid >> 4;
    int r0 = ty * 8, c0 = tx * 8;
    float acc[8][8];
    #pragma unroll
    for (int i = 0; i < 8; ++i)
        #pragma unroll
        for (int j = 0; j < 8; ++j) acc[i][j] = 0.0f;

    for (int d = 0; d < 64; ++d) {
        float a[8];
        #pragma unroll
        for (int i = 0; i < 8; ++i) a[i] = xs[r0 + i][d];
        float4 b0 = *(float4*)&wsm[d * 128 + c0];
        float4 b1 = *(float4*)&wsm[d * 128 + c0 + 4];
        float b[8] = {b0.x, b0.y, b0.z, b0.w, b1.x, b1.y, b1.z, b1.w};
        #pragma unroll
        for (int i = 0; i < 8; ++i)
            #pragma unroll
            for (int j = 0; j < 8; ++j)
                acc[i][j] = fmaf(a[i], b[j], acc[i][j]);
    }

    #pragma unroll
    for (int i = 0; i < 8; ++i) {
        float* dst = &h2[(base + r0 + i) * HID_C + c0];
        float4 o0 = {acc[i][0], acc[i][1], acc[i][2], acc[i][3]};
        float4 o1 = {acc[i][4], acc[i][5], acc[i][6], acc[i][7]};
        *(float4*)dst = o0;
        *(float4*)(dst + 4) = o1;
    }
}

// ------------------------------------------- SpMM out-of-place (primary) --
__global__ __launch_bounds__(256) void spmm_op(const float* __restrict__ ws_ro,
                                               const float* __restrict__ h2,
                                               const float* __restrict__ b1,
                                               float* __restrict__ rh) {
    int bid = blockIdx.x;
    int g = bid & 63, slice = bid >> 6;            // slice < 32
    int t = threadIdx.x;
    if (t >= 250) return;
    int p = slice * 250 + t;                       // < 8000
    int dst = p >> 3, chunk = p & 7, c0 = chunk << 4;

    const int*  rowp  = (const int*)(ws_ro + WS_ROWP) + g * 1024;
    const int2* pedge = (const int2*)(ws_ro + WS_PEDGE) + g * N_EDGES_C;
    const float* dinv = ws_ro + WS_DEG;

    int e0 = rowp[dst], e1 = rowp[dst + 1];
    float4 a0 = {0,0,0,0}, a1 = {0,0,0,0}, a2 = {0,0,0,0}, a3 = {0,0,0,0};
    for (int e = e0; e < e1; ++e) {
        int2 ed = pedge[e];
        float nm = __int_as_float(ed.y);
        const float* hp = &h2[ed.x * HID_C + c0];
        float4 h0 = *(const float4*)(hp + 0);
        float4 h1 = *(const float4*)(hp + 4);
        float4 h2v = *(const float4*)(hp + 8);
        float4 h3 = *(const float4*)(hp + 12);
        a0.x = fmaf(h0.x, nm, a0.x); a0.y = fmaf(h0.y, nm, a0.y);
        a0.z = fmaf(h0.z, nm, a0.z); a0.w = fmaf(h0.w, nm, a0.w);
        a1.x = fmaf(h1.x, nm, a1.x); a1.y = fmaf(h1.y, nm, a1.y);
        a1.z = fmaf(h1.z, nm, a1.z); a1.w = fmaf(h1.w, nm, a1.w);
        a2.x = fmaf(h2v.x, nm, a2.x); a2.y = fmaf(h2v.y, nm, a2.y);
        a2.z = fmaf(h2v.z, nm, a2.z); a2.w = fmaf(h2v.w, nm, a2.w);
        a3.x = fmaf(h3.x, nm, a3.x); a3.y = fmaf(h3.y, nm, a3.y);
        a3.z = fmaf(h3.z, nm, a3.z); a3.w = fmaf(h3.w, nm, a3.w);
    }

    int node = g * N_NODES_C + dst;
    float dv = dinv[node], dv2 = dv * dv;
    const float* sp = &h2[node * HID_C + c0];
    float* op = &rh[node * HID_C + c0];
    #pragma unroll
    for (int q = 0; q < 4; ++q) {
        float4 sv = *(const float4*)(sp + q * 4);
        float4 bv = *(const float4*)&b1[c0 + q * 4];
        float4 av = q == 0 ? a0 : q == 1 ? a1 : q == 2 ? a2 : a3;
        float4 o;
        o.x = fmaxf(fmaf(sv.x, dv2, av.x) + bv.x, 0.0f);
        o.y = fmaxf(fmaf(sv.y, dv2, av.y) + bv.y, 0.0f);
        o.z = fmaxf(fmaf(sv.z, dv2, av.z) + bv.z, 0.0f);
        o.w = fmaxf(fmaf(sv.w, dv2, av.w) + bv.w, 0.0f);
        *(float4*)(op + q * 4) = o;
    }
}

// ------------------------- SpMM in-place fallback (small ws): 1024 thr ----
__global__ __launch_bounds__(1024) void spmm_ip(const float* __restrict__ ws_ro,
                                                float* __restrict__ h2,
                                                const float* __restrict__ b1) {
    __shared__ float res[N_NODES_C * 16];          // 64000 B
    int bid = blockIdx.x;
    int g  = bid & 63;
    int c0 = (bid >> 6) * 16;
    int tid = threadIdx.x;
    int fq = tid & 3, dslot = tid >> 2;            // 256 dsts in flight

    const int*  rowp  = (const int*)(ws_ro + WS_ROWP) + g * 1024;
    const int2* pedge = (const int2*)(ws_ro + WS_PEDGE) + g * N_EDGES_C;
    const float* dinv = ws_ro + WS_DEG;
    int gbase = g * N_NODES_C;

    for (int iter = 0; iter < 4; ++iter) {
        int d = iter * 256 + dslot;
        if (d < N_NODES_C) {
            int e0 = rowp[d], e1 = rowp[d + 1];
            float4 a = make_float4(0.f, 0.f, 0.f, 0.f);
            for (int e = e0; e < e1; ++e) {
                int2 ed = pedge[e];
                float nm = __int_as_float(ed.y);
                float4 hv = *(const float4*)&h2[ed.x * HID_C + c0 + fq * 4];
                a.x = fmaf(hv.x, nm, a.x);
                a.y = fmaf(hv.y, nm, a.y);
                a.z = fmaf(hv.z, nm, a.z);
                a.w = fmaf(hv.w, nm, a.w);
            }
            *(float4*)&res[d * 16 + fq * 4] = a;
        }
    }
    __syncthreads();

    for (int idx = tid; idx < N_NODES_C * 16; idx += 1024) {
        int v = idx >> 4, f = idx & 15;
        int node = gbase + v;
        float dv = dinv[node];
        float val = res[idx] + h2[node * HID_C + c0 + f] * (dv * dv) + b1[c0 + f];
        h2[node * HID_C + c0 + f] = fmaxf(val, 0.0f);
    }
}

// ------------------------------------------- g partials: rh @ Wn chunks ---
// 800 blocks (~3/CU -> 12 waves/CU, was 1/CU) x k-chunk 160; 8-k steps keep
// 16 rh float4 + 8 Wn loads in flight. Partials overlap dead CSR region.
__global__ __launch_bounds__(256) void reduce_g(const float* __restrict__ rh,
                                                const float* __restrict__ Wn,
                                                float* __restrict__ part) {
    int tid = threadIdx.x;
    int j = tid & 31, bg = tid >> 5;               // bg: 8 graphs each
    int k0 = blockIdx.x * 160;
    float acc[8] = {0, 0, 0, 0, 0, 0, 0, 0};
    for (int kk = 0; kk < 160; kk += 8) {
        int k = k0 + kk;
        float w[8];
        #pragma unroll
        for (int q = 0; q < 8; ++q) w[q] = Wn[(k + q) * 32 + j];
        #pragma unroll
        for (int u = 0; u < 8; ++u) {
            const float* rp = &rh[(bg * 8 + u) * 128000 + k];
            float4 r0 = *(const float4*)(rp + 0);
            float4 r1 = *(const float4*)(rp + 4);
            acc[u] = fmaf(r0.x, w[0], acc[u]);
            acc[u] = fmaf(r0.y, w[1], acc[u]);
            acc[u] = fmaf(r0.z, w[2], acc[u]);
            acc[u] = fmaf(r0.w, w[3], acc[u]);
            acc[u] = fmaf(r1.x, w[4], acc[u]);
            acc[u] = fmaf(r1.y, w[5], acc[u]);
            acc[u] = fmaf(r1.z, w[6], acc[u]);
            acc[u] = fmaf(r1.w, w[7], acc[u]);
        }
    }
    #pragma unroll
    for (int u = 0; u < 8; ++u)
        part[blockIdx.x * 2048 + (bg * 8 + u) * 32 + j] = acc[u];
}

// ---------------------- final: sum partials, +bn, @Wc, +bc ----------------
// 64 blocks (one per graph): 8 c-lanes x 32 j; LDS + shfl reduce.
__global__ __launch_bounds__(256) void final_out(const float* __restrict__ ws_ro,
                                                 const float* __restrict__ bn,
                                                 const float* __restrict__ Wc,
                                                 const float* __restrict__ bc,
                                                 float* __restrict__ out) {
    __shared__ float red[256];
    int g = blockIdx.x;
    int tid = threadIdx.x;
    int j = tid & 31, cl = tid >> 5;               // 8 c-lanes
    const float* part = ws_ro + WS_PART2;
    float s = 0.0f;
    for (int c = cl; c < RG_BLOCKS; c += 8)
        s += part[c * 2048 + g * 32 + j];
    red[tid] = s;
    __syncthreads();
    if (tid < 32) {
        float gv = red[tid];
        #pragma unroll
        for (int q = 1; q < 8; ++q) gv += red[q * 32 + tid];
        gv += bn[tid];
        float o0 = gv * Wc[tid * 2 + 0];
        float o1 = gv * Wc[tid * 2 + 1];
        #pragma unroll
        for (int off = 16; off >= 1; off >>= 1) {
            o0 += __shfl_xor(o0, off);
            o1 += __shfl_xor(o1, off);
        }
        if (tid == 0) {
            out[g * 2 + 0] = o0 + bc[0];
            out[g * 2 + 1] = o1 + bc[1];
        }
    }
}

// --------------------------------------------------------------------------
extern "C" void kernel_launch(void* const* d_in, const int* in_sizes, int n_in,
                              void* d_out, int out_size, void* d_ws, size_t ws_size,
                              hipStream_t stream) {
    const float* x  = (const float*)d_in[0];
    const int*   ei = (const int*)d_in[1];
    const float* ew = (const float*)d_in[3];
    const float* ni = (const float*)d_in[4];
    const float* W1 = (const float*)d_in[5];
    const float* b1 = (const float*)d_in[6];
    const float* Wn = (const float*)d_in[7];
    const float* bn = (const float*)d_in[8];
    const float* Wc = (const float*)d_in[9];
    const float* bc = (const float*)d_in[10];
    float* out = (float*)d_out;
    float* ws  = (float*)d_ws;

    bool big = ws_size >= (size_t)(WS_RH + 8192000) * sizeof(float);
    float* h2 = ws + WS_H2;
    float* rh = big ? ws + WS_RH : h2;

    prep<<<NT / 256, 256, 0, stream>>>(ew, ni, ws, out);
    gemm_h2<<<NT / 128, 256, 0, stream>>>(x, ni, W1, h2);
    deg_cnt<<<ET / 256, 256, 0, stream>>>(ei, ws);
    csr_scan<<<BATCH_C, 256, 0, stream>>>(ws);
    scatter<<<ET / 256, 256, 0, stream>>>(ei, ws);
    if (big)
        spmm_op<<<BATCH_C * 32, 256, 0, stream>>>(ws, h2, b1, rh);
    else
        spmm_ip<<<BATCH_C * 8, 1024, 0, stream>>>(ws, h2, b1);
    reduce_g<<<RG_BLOCKS, 256, 0, stream>>>(rh, Wn, ws + WS_PART2);
    final_out<<<BATCH_C, 256, 0, stream>>>(ws, bn, Wc, bc, out);
}